// Round 1
// baseline (940.813 us; speedup 1.0000x reference)
//
#include <hip/hip_runtime.h>
#include <cmath>

#define NPOS 16384      // b*n
#define ATT_SCALE 0.125f    // 64^-0.5

// Generic fp32 tiled GEMM: C[row, co+n] = sum_k A[row, ao+k] * B(k,n) (+bias)
//   normal: B(k,n) = B[(bk0+k)*ldb + bn0+n]
//   trans : B(k,n) = B[(bn0+n)*ldb + bk0+k]
// Per-z offsets: ao = ao0 + z*az; bk0 = bk00 + z*bkz; bn0 = bn00 + z*bnz + nt*64;
//                co = co0 + z*cz + nt*64.
// Tile 64x64, K-step 16, 256 threads, 4x4 acc per thread. All dims divide evenly.
template<bool BTRANS, bool BIAS>
__global__ __launch_bounds__(256) void gemm_f32(
    const float* __restrict__ A, int lda, int ao0, int az,
    const float* __restrict__ B, int ldb, int bk00, int bkz, int bn00, int bnz,
    float* __restrict__ C, int ldc, int co0, int cz,
    const float* __restrict__ bias, int K)
{
    __shared__ float As[64][17];
    __shared__ float Bs[16][65];
    const int tid = threadIdx.x;
    const int mt = blockIdx.x, nt = blockIdx.y, z = blockIdx.z;
    const int ao  = ao0 + z * az;
    const int bk0 = bk00 + z * bkz;
    const int bn0 = bn00 + z * bnz + nt * 64;
    const int co  = co0 + z * cz + nt * 64;
    const int row0 = mt * 64;
    const int tx = tid & 15, ty = tid >> 4;

    float acc[4][4] = {};

    for (int k0 = 0; k0 < K; k0 += 16) {
        #pragma unroll
        for (int it = 0; it < 4; ++it) {
            int i = tid + it * 256;
            int r = i >> 4, kk = i & 15;
            As[r][kk] = A[(size_t)(row0 + r) * lda + (ao + k0 + kk)];
        }
        if (BTRANS) {
            #pragma unroll
            for (int it = 0; it < 4; ++it) {
                int i = tid + it * 256;
                int n = i >> 4, kk = i & 15;
                Bs[kk][n] = B[(size_t)(bn0 + n) * ldb + (bk0 + k0 + kk)];
            }
        } else {
            #pragma unroll
            for (int it = 0; it < 4; ++it) {
                int i = tid + it * 256;
                int kk = i >> 6, n = i & 63;
                Bs[kk][n] = B[(size_t)(bk0 + k0 + kk) * ldb + (bn0 + n)];
            }
        }
        __syncthreads();
        #pragma unroll
        for (int kk = 0; kk < 16; ++kk) {
            float a[4], b[4];
            #pragma unroll
            for (int i = 0; i < 4; ++i) a[i] = As[ty * 4 + i][kk];
            #pragma unroll
            for (int j = 0; j < 4; ++j) b[j] = Bs[kk][tx * 4 + j];
            #pragma unroll
            for (int i = 0; i < 4; ++i)
                #pragma unroll
                for (int j = 0; j < 4; ++j)
                    acc[i][j] = fmaf(a[i], b[j], acc[i][j]);
        }
        __syncthreads();
    }

    #pragma unroll
    for (int i = 0; i < 4; ++i) {
        float4 v;
        v.x = acc[i][0]; v.y = acc[i][1]; v.z = acc[i][2]; v.w = acc[i][3];
        if (BIAS) {
            const float4 bv = *(const float4*)&bias[co + tx * 4];
            v.x += bv.x; v.y += bv.y; v.z += bv.z; v.w += bv.w;
        }
        *(float4*)&C[(size_t)(row0 + ty * 4 + i) * ldc + (co + tx * 4)] = v;
    }
}

// Per-position attention: one 64-lane wave per position p.
// In:  y [NPOS,16,256] fp32, qk [NPOS,8,256] fp32 (qk[p,h,c])
// Out: ybar overwrites qk in place: ybar[p,h,c] = sum_m softmax_m(SCALE*qk.y)[h,m] * y[p,m,c]
__global__ __launch_bounds__(64) void attn_f32(
    const float* __restrict__ y,
    float* __restrict__ qk)
{
    __shared__ float ylds[16][260];   // pad to multiple of 4 for float4 LDS reads
    __shared__ float qlds[8][260];
    __shared__ float attn_s[8][16];
    __shared__ float dots_s[8][16];
    const int p = blockIdx.x;
    const int lane = threadIdx.x;
    const float* yp = y + (size_t)p * 4096;
    float* qkp = qk + (size_t)p * 2048;

    // stage y (16x256) and qk (8x256) into LDS, float4-coalesced
    for (int i = lane; i < 1024; i += 64) {
        float4 v = ((const float4*)yp)[i];
        int m = i >> 6, c4 = (i & 63) * 4;
        *(float4*)&ylds[m][c4] = v;
    }
    for (int i = lane; i < 512; i += 64) {
        float4 v = ((const float4*)qkp)[i];
        int h = i >> 6, c4 = (i & 63) * 4;
        *(float4*)&qlds[h][c4] = v;
    }
    __syncthreads();

    // dots[h,m] = SCALE * sum_c qk[h,c]*y[m,c]; lane = m*4+cg, cg covers 64 c's
    const int m = lane >> 2, cg = lane & 3;
    #pragma unroll
    for (int h = 0; h < 8; ++h) {
        float s = 0.f;
        #pragma unroll
        for (int j = 0; j < 16; ++j) {
            const float4 qv = *(const float4*)&qlds[h][cg * 64 + j * 4];
            const float4 yv = *(const float4*)&ylds[m][cg * 64 + j * 4];
            s += qv.x * yv.x + qv.y * yv.y + qv.z * yv.z + qv.w * yv.w;
        }
        s += __shfl_xor(s, 1);
        s += __shfl_xor(s, 2);
        if (cg == 0) dots_s[h][m] = s * ATT_SCALE;
    }
    __syncthreads();

    // softmax over m per head; lanes 0..7 each own one head (trivial cost)
    if (lane < 8) {
        const int h = lane;
        float mx = -1e30f;
        #pragma unroll
        for (int mm = 0; mm < 16; ++mm) mx = fmaxf(mx, dots_s[h][mm]);
        float e[16]; float sum = 0.f;
        #pragma unroll
        for (int mm = 0; mm < 16; ++mm) { e[mm] = __expf(dots_s[h][mm] - mx); sum += e[mm]; }
        const float inv = 1.f / sum;
        #pragma unroll
        for (int mm = 0; mm < 16; ++mm) attn_s[h][mm] = e[mm] * inv;
    }
    __syncthreads();

    // ybar[h,c] = sum_m attn[h,m]*y[m,c]; lane owns c = lane*4..+3, write over qk
    #pragma unroll
    for (int h = 0; h < 8; ++h) {
        float4 a = {0.f, 0.f, 0.f, 0.f};
        #pragma unroll
        for (int mm = 0; mm < 16; ++mm) {
            const float w = attn_s[h][mm];
            const float4 yv = *(const float4*)&ylds[mm][lane * 4];
            a.x = fmaf(w, yv.x, a.x); a.y = fmaf(w, yv.y, a.y);
            a.z = fmaf(w, yv.z, a.z); a.w = fmaf(w, yv.w, a.w);
        }
        ((float4*)qkp)[h * 64 + lane] = a;
    }
}

extern "C" void kernel_launch(void* const* d_in, const int* in_sizes, int n_in,
                              void* d_out, int out_size, void* d_ws, size_t ws_size,
                              hipStream_t stream)
{
    (void)in_sizes; (void)n_in; (void)out_size; (void)ws_size;
    const float* x     = (const float*)d_in[0];   // [8,2048,256]
    const float* y     = (const float*)d_in[1];   // [8,2048,16,256]
    const float* W_q   = (const float*)d_in[2];   // [256,512]
    const float* W_kv  = (const float*)d_in[3];   // [256,1024]
    const float* W_out = (const float*)d_in[4];   // [512,256]
    const float* b_out = (const float*)d_in[5];   // [256]
    float* out = (float*)d_out;                   // [16384,256]

    // workspace: qk/ybar [16384,2048] then q/o [16384,512] (~168 MB total)
    float* qk   = (float*)d_ws;
    float* qbuf = qk + (size_t)NPOS * 2048;

    dim3 blk(256);

    // K1: q = x @ W_q            [16384,256] x [256,512] -> qbuf [16384,512]
    gemm_f32<false, false><<<dim3(256, 8, 1), blk, 0, stream>>>(
        x, 256, 0, 0,   W_q, 512, 0, 0, 0, 0,   qbuf, 512, 0, 0, nullptr, 256);

    // K2: qk[p,h,c] = sum_d q[p,h*64+d] * W_kv[c, h*64+d]   (z = head)
    gemm_f32<true, false><<<dim3(256, 4, 8), blk, 0, stream>>>(
        qbuf, 512, 0, 64,   W_kv, 1024, 0, 64, 0, 0,   qk, 2048, 0, 256, nullptr, 64);

    // K3: dots -> softmax -> ybar (in place over qk)
    attn_f32<<<dim3(NPOS), dim3(64), 0, stream>>>(y, qk);

    // K4: o[p,h*64+d] = sum_c ybar[p,h,c] * W_kv[c, 512+h*64+d]  (o into qbuf)
    gemm_f32<false, false><<<dim3(256, 1, 8), blk, 0, stream>>>(
        qk, 2048, 0, 256,   W_kv, 1024, 0, 0, 512, 64,   qbuf, 512, 0, 64, nullptr, 256);

    // K5: out = o @ W_out + b_out   [16384,512] x [512,256]
    gemm_f32<false, true><<<dim3(256, 4, 1), blk, 0, stream>>>(
        qbuf, 512, 0, 0,   W_out, 256, 0, 0, 0, 0,   out, 256, 0, 0, b_out, 512);
}

// Round 2
// 761.392 us; speedup vs baseline: 1.2356x; 1.2356x over previous
//
#include <hip/hip_runtime.h>
#include <cmath>

#define NPOS 16384
#define ATT_SCALE 0.125f

typedef float f4 __attribute__((ext_vector_type(4)));
typedef short short8 __attribute__((ext_vector_type(8)));

__device__ inline ushort f2bf(float f) {
    union { float f; uint u; } v; v.f = f;
    uint r = v.u + 0x7fffu + ((v.u >> 16) & 1u);
    return (ushort)(r >> 16);
}
__device__ inline float bfl(uint u) { union { uint u; float f; } v; v.u = u << 16; return v.f; }
__device__ inline float bfh(uint u) { union { uint u; float f; } v; v.u = u & 0xffff0000u; return v.f; }

// ---------------------------------------------------------------------------
// bf16 MFMA GEMM: C[row, co+n] = sum_k A[row, ao+k] * Bt[bn0+n, bk0+k]
// Bt is bf16 [N][K] (row-major along k). A is fp32 or bf16 row-major [M][lda].
// Tile: BM=128, BN=64, BK=32. 256 threads = 4 waves; wave w: rows w*32..+31,
// all 64 cols (2 m-subtiles x 4 n-subtiles of 16x16, MFMA 16x16x32 bf16).
// Per-z offsets: ao=ao0+z*az, bk0=bk00+z*bkz, bn0=bn00+z*bnz+nt*64,
//                co=co0+z*cz+nt*64.
// ---------------------------------------------------------------------------
template<bool A_F32, bool C_F32>
__global__ __launch_bounds__(256) void gemm_mfma(
    const void* __restrict__ Ag, int lda, int ao0, int az,
    const ushort* __restrict__ Bt, int ldb, int bk00, int bkz, int bn00, int bnz,
    void* __restrict__ Cg, int ldc, int co0, int cz,
    const float* __restrict__ bias, int K)
{
    // row stride 40 shorts = 80 B = odd multiple of 16 B -> b128 frag reads are
    // 16B-aligned and spread over all 8 bank-quads (2-way max = free).
    __shared__ __align__(16) ushort A_lds[128 * 40];
    __shared__ __align__(16) ushort B_lds[64 * 40];
    const int tid = threadIdx.x;
    const int mt = blockIdx.x, nt = blockIdx.y, z = blockIdx.z;
    const int ao  = ao0 + z * az;
    const int bk0 = bk00 + z * bkz;
    const int bn0 = bn00 + z * bnz + nt * 64;
    const int co  = co0 + z * cz + nt * 64;
    const int row0 = mt * 128;
    const int lane = tid & 63, w = tid >> 6;
    const int frow = lane & 15, quad = lane >> 4;

    f4 acc[2][4];
    #pragma unroll
    for (int mi = 0; mi < 2; ++mi)
        #pragma unroll
        for (int ni = 0; ni < 4; ++ni)
            acc[mi][ni] = (f4){0.f, 0.f, 0.f, 0.f};

    for (int k0 = 0; k0 < K; k0 += 32) {
        // ---- stage A (128 x 32) ----
        if (A_F32) {
            const float* A = (const float*)Ag;
            const int kp = (tid & 15) * 2;
            const int rbase = tid >> 4;
            #pragma unroll
            for (int r = 0; r < 8; ++r) {
                int row = rbase + r * 16;
                float2 v = *(const float2*)&A[(size_t)(row0 + row) * lda + ao + k0 + kp];
                uint packed = (uint)f2bf(v.x) | ((uint)f2bf(v.y) << 16);
                *(uint*)&A_lds[row * 40 + kp] = packed;
            }
        } else {
            const ushort* A = (const ushort*)Ag;
            const int kq = (tid & 7) * 4;
            const int rbase = tid >> 3;
            #pragma unroll
            for (int r = 0; r < 4; ++r) {
                int row = rbase + r * 32;
                uint2 v = *(const uint2*)&A[(size_t)(row0 + row) * lda + ao + k0 + kq];
                *(uint2*)&A_lds[row * 40 + kq] = v;
            }
        }
        // ---- stage B (64 x 32) from bf16 [n][k] ----
        {
            const int kq = (tid & 7) * 4;
            const int nbase = tid >> 3;
            #pragma unroll
            for (int r = 0; r < 2; ++r) {
                int n = nbase + r * 32;
                uint2 v = *(const uint2*)&Bt[(size_t)(bn0 + n) * ldb + bk0 + k0 + kq];
                *(uint2*)&B_lds[n * 40 + kq] = v;
            }
        }
        __syncthreads();

        short8 a0 = *(const short8*)&A_lds[(w * 32 + frow) * 40 + quad * 8];
        short8 a1 = *(const short8*)&A_lds[(w * 32 + 16 + frow) * 40 + quad * 8];
        #pragma unroll
        for (int ni = 0; ni < 4; ++ni) {
            short8 b = *(const short8*)&B_lds[(ni * 16 + frow) * 40 + quad * 8];
            acc[0][ni] = __builtin_amdgcn_mfma_f32_16x16x32_bf16(a0, b, acc[0][ni], 0, 0, 0);
            acc[1][ni] = __builtin_amdgcn_mfma_f32_16x16x32_bf16(a1, b, acc[1][ni], 0, 0, 0);
        }
        __syncthreads();
    }

    // ---- epilogue: reg i -> row=quad*4+i, col=lane&15 ----
    #pragma unroll
    for (int mi = 0; mi < 2; ++mi)
        #pragma unroll
        for (int i = 0; i < 4; ++i) {
            int row = row0 + w * 32 + mi * 16 + quad * 4 + i;
            #pragma unroll
            for (int ni = 0; ni < 4; ++ni) {
                int col = co + ni * 16 + frow;
                float v = acc[mi][ni][i];
                if (C_F32) {
                    float b = bias ? bias[col] : 0.f;
                    ((float*)Cg)[(size_t)row * ldc + col] = v + b;
                } else {
                    ((ushort*)Cg)[(size_t)row * ldc + col] = f2bf(v);
                }
            }
        }
}

// ---------------------------------------------------------------------------
// Weight prep: transpose/convert fp32 weights to bf16 [n][k] layouts.
//   WqT  [512][256] = Wq^T ;  WkvB [256][1024] = Wkv (convert only)
//   WkvT [1024][256] = Wkv^T; WoutT[256][512]  = Wout^T
// ---------------------------------------------------------------------------
__global__ __launch_bounds__(256) void prep_weights(
    const float* __restrict__ Wq, const float* __restrict__ Wkv,
    const float* __restrict__ Wout,
    ushort* __restrict__ WqT, ushort* __restrict__ WkvB,
    ushort* __restrict__ WkvT, ushort* __restrict__ WoutT)
{
    int i = blockIdx.x * 256 + threadIdx.x;
    if (i < 131072) {
        int n = i >> 8, k = i & 255;
        WqT[i] = f2bf(Wq[k * 512 + n]);
    } else if (i < 393216) {
        int j = i - 131072;
        WkvB[j] = f2bf(Wkv[j]);
    } else if (i < 655360) {
        int j = i - 393216;
        int r = j >> 8, c = j & 255;
        WkvT[j] = f2bf(Wkv[c * 1024 + r]);
    } else {
        int j = i - 655360;
        int n = j >> 9, k = j & 511;
        WoutT[j] = f2bf(Wout[k * 256 + n]);
    }
}

// ---------------------------------------------------------------------------
// Attention: 4 waves/block, one position per wave. qk (bf16) read, ybar (bf16)
// written in place. y read direct from global (16 KB/pos, L1-resident for the
// second pass). Only 4 KB LDS -> occupancy VGPR-bound.
// ---------------------------------------------------------------------------
__global__ __launch_bounds__(256) void attn_k(
    const float* __restrict__ y, ushort* __restrict__ qk)
{
    __shared__ float dots_s[4][8][16];
    __shared__ float attn_s[4][8][16];
    const int w = threadIdx.x >> 6, lane = threadIdx.x & 63;
    const int p = blockIdx.x * 4 + w;
    const float* yp = y + (size_t)p * 4096;
    ushort* qkp = qk + (size_t)p * 2048;

    // dots[h,m] = SCALE * sum_c qk[h,c]*y[m,c]; lane: m=l>>2, cg=l&3 (64 c each)
    const int m = lane >> 2, cg = lane & 3;
    #pragma unroll
    for (int h = 0; h < 8; ++h) {
        float s = 0.f;
        #pragma unroll
        for (int j = 0; j < 16; ++j) {
            uint2 qv = *(const uint2*)&qkp[h * 256 + cg * 64 + j * 4];
            float4 yv = *(const float4*)&yp[m * 256 + cg * 64 + j * 4];
            s += bfl(qv.x) * yv.x + bfh(qv.x) * yv.y + bfl(qv.y) * yv.z + bfh(qv.y) * yv.w;
        }
        s += __shfl_xor(s, 1);
        s += __shfl_xor(s, 2);
        if (cg == 0) dots_s[w][h][m] = s * ATT_SCALE;
    }
    __syncthreads();

    if (lane < 8) {
        const int h = lane;
        float mx = -1e30f;
        #pragma unroll
        for (int mm = 0; mm < 16; ++mm) mx = fmaxf(mx, dots_s[w][h][mm]);
        float e[16]; float sum = 0.f;
        #pragma unroll
        for (int mm = 0; mm < 16; ++mm) { e[mm] = __expf(dots_s[w][h][mm] - mx); sum += e[mm]; }
        float inv = 1.f / sum;
        #pragma unroll
        for (int mm = 0; mm < 16; ++mm) attn_s[w][h][mm] = e[mm] * inv;
    }
    __syncthreads();

    // ybar[h, c] = sum_m attn[h,m]*y[m,c]; lane owns c = lane*4..+3
    float4 acc[8];
    #pragma unroll
    for (int h = 0; h < 8; ++h) acc[h] = make_float4(0.f, 0.f, 0.f, 0.f);
    #pragma unroll
    for (int mm = 0; mm < 16; ++mm) {
        float4 yv = *(const float4*)&yp[mm * 256 + lane * 4];
        #pragma unroll
        for (int h = 0; h < 8; ++h) {
            float aw = attn_s[w][h][mm];
            acc[h].x = fmaf(aw, yv.x, acc[h].x);
            acc[h].y = fmaf(aw, yv.y, acc[h].y);
            acc[h].z = fmaf(aw, yv.z, acc[h].z);
            acc[h].w = fmaf(aw, yv.w, acc[h].w);
        }
    }
    #pragma unroll
    for (int h = 0; h < 8; ++h) {
        uint2 pv;
        pv.x = (uint)f2bf(acc[h].x) | ((uint)f2bf(acc[h].y) << 16);
        pv.y = (uint)f2bf(acc[h].z) | ((uint)f2bf(acc[h].w) << 16);
        *(uint2*)&qkp[h * 256 + lane * 4] = pv;
    }
}

extern "C" void kernel_launch(void* const* d_in, const int* in_sizes, int n_in,
                              void* d_out, int out_size, void* d_ws, size_t ws_size,
                              hipStream_t stream)
{
    (void)in_sizes; (void)n_in; (void)out_size; (void)ws_size;
    const float* x     = (const float*)d_in[0];   // [16384,256]
    const float* y     = (const float*)d_in[1];   // [16384,16,256]
    const float* W_q   = (const float*)d_in[2];   // [256,512]
    const float* W_kv  = (const float*)d_in[3];   // [256,1024]
    const float* W_out = (const float*)d_in[4];   // [512,256]
    const float* b_out = (const float*)d_in[5];   // [256]
    float* out = (float*)d_out;                   // [16384,256]

    // workspace (bf16): qk/ybar [16384,2048], q [16384,512], o [16384,512],
    // then bf16 weights. Total ~102 MB.
    ushort* qk   = (ushort*)d_ws;
    ushort* q    = qk + (size_t)NPOS * 2048;
    ushort* o    = q  + (size_t)NPOS * 512;
    ushort* WqT  = o  + (size_t)NPOS * 512;
    ushort* WkvB = WqT  + 512 * 256;
    ushort* WkvT = WkvB + 256 * 1024;
    ushort* WoutT= WkvT + 1024 * 256;

    dim3 blk(256);

    prep_weights<<<dim3(3072), blk, 0, stream>>>(W_q, W_kv, W_out, WqT, WkvB, WkvT, WoutT);

    // K1: q = x @ W_q  (A fp32, C bf16)   [16384,256]x[256,512]
    gemm_mfma<true, false><<<dim3(128, 8, 1), blk, 0, stream>>>(
        x, 256, 0, 0,  WqT, 256, 0, 0, 0, 0,  q, 512, 0, 0, nullptr, 256);

    // K2: qk[p, z*256+c] = sum_d q[p, 64z+d] * Wkv[c, 64z+d]   (z = head)
    gemm_mfma<false, false><<<dim3(128, 4, 8), blk, 0, stream>>>(
        q, 512, 0, 64,  WkvB, 1024, 0, 64, 0, 0,  qk, 2048, 0, 256, nullptr, 64);

    // K3: dots -> softmax -> ybar (in place over qk)
    attn_k<<<dim3(NPOS / 4), blk, 0, stream>>>(y, qk);

    // K4: o[p, 64z+d] = sum_c ybar[p, 256z+c] * Wkv[c, 512+64z+d]
    gemm_mfma<false, false><<<dim3(128, 1, 8), blk, 0, stream>>>(
        qk, 2048, 0, 256,  WkvT, 256, 0, 0, 512, 64,  o, 512, 0, 64, nullptr, 256);

    // K5: out = o @ W_out + b_out  (C fp32)
    gemm_mfma<false, true><<<dim3(128, 4, 1), blk, 0, stream>>>(
        o, 512, 0, 0,  WoutT, 512, 0, 0, 0, 0,  out, 256, 0, 0, b_out, 512);
}

// Round 3
// 522.961 us; speedup vs baseline: 1.7990x; 1.4559x over previous
//
#include <hip/hip_runtime.h>
#include <cmath>

#define NPOS 16384
#define ATT_SCALE 0.125f

typedef float f4 __attribute__((ext_vector_type(4)));
typedef short short8 __attribute__((ext_vector_type(8)));
typedef unsigned int uint;
typedef unsigned short ushort;

__device__ __forceinline__ ushort f2bf(float f) {
    union { float f; uint u; } v; v.f = f;
    uint r = v.u + 0x7fffu + ((v.u >> 16) & 1u);
    return (ushort)(r >> 16);
}
__device__ __forceinline__ float bfl(uint u) { union { uint u; float f; } v; v.u = u << 16; return v.f; }
__device__ __forceinline__ float bfh(uint u) { union { uint u; float f; } v; v.u = u & 0xffff0000u; return v.f; }

// async global->LDS, 16B per lane; LDS dest = base + lane*16 (wave-uniform base)
__device__ __forceinline__ void gl_lds16(const ushort* g, ushort* l) {
    __builtin_amdgcn_global_load_lds(
        (const __attribute__((address_space(1))) uint*)g,
        (__attribute__((address_space(3))) uint*)l, 16, 0, 0);
}

// ---------------------------------------------------------------------------
// bf16 MFMA GEMM (m97-style): C[M,N] = A[M,K] @ Bt[N,K]^T (+bias)
// BM=128, BN = 128 or 64, BK=32, 256 threads = 4 waves.
// MFMA operands swapped -> acc holds C^T: lane frow = C-row, (quad*4+i) = C-col
// so each lane owns 4 consecutive C columns -> packed stores.
// grid: blockIdx.x = nt (fast, shares A tile for L2 reuse), blockIdx.y = mt.
// ---------------------------------------------------------------------------
template<int BN, bool C_F32, bool BIAS>
__global__ __launch_bounds__(256) void gemm_bt(
    const ushort* __restrict__ A, int lda,
    const ushort* __restrict__ Bt, int ldb,
    void* __restrict__ Cg, int ldc,
    const float* __restrict__ bias, int K)
{
    constexpr int NSUB = BN / 16;
    __shared__ __align__(16) ushort A_lds[128 * 32];
    __shared__ __align__(16) ushort B_lds[BN * 32];
    const int nt = blockIdx.x, mt = blockIdx.y;
    const int row0 = mt * 128, col0 = nt * BN;
    const int tid = threadIdx.x;
    const int lane = tid & 63, w = tid >> 6;
    const int frow = lane & 15, quad = lane >> 4;
    const int lrow = lane >> 2, lk = (lane & 3) * 8;

    f4 acc[2][NSUB];
    #pragma unroll
    for (int mi = 0; mi < 2; ++mi)
        #pragma unroll
        for (int ni = 0; ni < NSUB; ++ni)
            acc[mi][ni] = (f4){0.f, 0.f, 0.f, 0.f};

    for (int k0 = 0; k0 < K; k0 += 32) {
        // stage A: 128 rows x 32 k (8 KB) = 2 issues/wave
        #pragma unroll
        for (int it = 0; it < 2; ++it) {
            int start = w * 16 + it * 64;
            gl_lds16(A + (size_t)(row0 + start + lrow) * lda + k0 + lk,
                     &A_lds[start * 32]);
        }
        // stage B: BN rows x 32 k
        #pragma unroll
        for (int it = 0; it < BN / 64; ++it) {
            int start = w * 16 + it * 64;
            gl_lds16(Bt + (size_t)(col0 + start + lrow) * ldb + k0 + lk,
                     &B_lds[start * 32]);
        }
        __syncthreads();

        short8 a0 = *(const short8*)&A_lds[(w * 32 + frow) * 32 + quad * 8];
        short8 a1 = *(const short8*)&A_lds[(w * 32 + 16 + frow) * 32 + quad * 8];
        #pragma unroll
        for (int ni = 0; ni < NSUB; ++ni) {
            short8 b = *(const short8*)&B_lds[(ni * 16 + frow) * 32 + quad * 8];
            // swapped operands: acc = C^T fragments
            acc[0][ni] = __builtin_amdgcn_mfma_f32_16x16x32_bf16(b, a0, acc[0][ni], 0, 0, 0);
            acc[1][ni] = __builtin_amdgcn_mfma_f32_16x16x32_bf16(b, a1, acc[1][ni], 0, 0, 0);
        }
        __syncthreads();
    }

    // epilogue: C row = row0 + w*32 + mi*16 + frow; cols = col0 + ni*16 + quad*4 .. +3
    #pragma unroll
    for (int mi = 0; mi < 2; ++mi) {
        const int r = row0 + w * 32 + mi * 16 + frow;
        #pragma unroll
        for (int ni = 0; ni < NSUB; ++ni) {
            const int c = col0 + ni * 16 + quad * 4;
            f4 v = acc[mi][ni];
            if (C_F32) {
                float* C = (float*)Cg;
                if (BIAS) {
                    const float4 bv = *(const float4*)&bias[c];
                    v[0] += bv.x; v[1] += bv.y; v[2] += bv.z; v[3] += bv.w;
                }
                *(float4*)&C[(size_t)r * ldc + c] = make_float4(v[0], v[1], v[2], v[3]);
            } else {
                ushort* C = (ushort*)Cg;
                uint2 pv;
                pv.x = (uint)f2bf(v[0]) | ((uint)f2bf(v[1]) << 16);
                pv.y = (uint)f2bf(v[2]) | ((uint)f2bf(v[3]) << 16);
                *(uint2*)&C[(size_t)r * ldc + c] = pv;
            }
        }
    }
}

// ---------------------------------------------------------------------------
// prep_x: x fp32 -> bf16, 8 elems/thread
// ---------------------------------------------------------------------------
__global__ __launch_bounds__(256) void prep_x(
    const float* __restrict__ x, ushort* __restrict__ xb)
{
    const int i = (blockIdx.x * 256 + threadIdx.x) * 8;
    float4 v0 = *(const float4*)&x[i];
    float4 v1 = *(const float4*)&x[i + 4];
    uint4 p;
    p.x = (uint)f2bf(v0.x) | ((uint)f2bf(v0.y) << 16);
    p.y = (uint)f2bf(v0.z) | ((uint)f2bf(v0.w) << 16);
    p.z = (uint)f2bf(v1.x) | ((uint)f2bf(v1.y) << 16);
    p.w = (uint)f2bf(v1.z) | ((uint)f2bf(v1.w) << 16);
    *(uint4*)&xb[i] = p;
}

// ---------------------------------------------------------------------------
// prep_w: fused weights.
//  Wf1n [n=h*256+c][k=e] = sum_d W_q[e,64h+d] * W_kv[c,64h+d]       (bf16)
//  Wf2t [n=e][k=h*256+c] = sum_d W_kv[c,512+64h+d] * W_out[64h+d,e] (bf16)
// ---------------------------------------------------------------------------
__global__ __launch_bounds__(256) void prep_w(
    const float* __restrict__ Wq, const float* __restrict__ Wkv,
    const float* __restrict__ Wout,
    ushort* __restrict__ Wf1n, ushort* __restrict__ Wf2t)
{
    const int t = blockIdx.x * 256 + threadIdx.x;
    if (t < 524288) {
        const int n = t >> 8, e = t & 255;
        const int h = n >> 8, c = n & 255;
        const float* wq = &Wq[e * 512 + h * 64];
        const float* wv = &Wkv[c * 1024 + h * 64];
        float s = 0.f;
        #pragma unroll 8
        for (int d = 0; d < 64; ++d) s = fmaf(wq[d], wv[d], s);
        Wf1n[t] = f2bf(s);
    } else {
        const int j = t - 524288;
        const int e = j >> 11, kk = j & 2047;
        const int h = kk >> 8, c = kk & 255;
        const float* wv = &Wkv[c * 1024 + 512 + h * 64];
        const float* wo = &Wout[h * 64 * 256 + e];
        float s = 0.f;
        #pragma unroll 8
        for (int d = 0; d < 64; ++d) s = fmaf(wv[d], wo[d * 256], s);
        Wf2t[(size_t)e * 2048 + kk] = f2bf(s);
    }
}

// ---------------------------------------------------------------------------
// attn: one position per 256-thread block. y (16 KB) + qk staged to LDS once;
// dots -> softmax -> ybar; ybar overwrites qk (bf16). y read from HBM once.
// ---------------------------------------------------------------------------
__global__ __launch_bounds__(256) void attn_k(
    const float* __restrict__ y, ushort* __restrict__ qk)
{
    __shared__ float ylds[16 * 260];
    __shared__ float qkf[8 * 260];
    __shared__ float part[4][8][16];
    __shared__ __align__(16) float attn_sT[16][8];
    const int p = blockIdx.x;
    const int t = threadIdx.x;
    const int w = t >> 6, lane = t & 63;
    const float* yp = y + (size_t)p * 4096;
    ushort* qkp = qk + (size_t)p * 2048;

    // stage y fp32 (coalesced float4)
    #pragma unroll
    for (int it = 0; it < 4; ++it) {
        int i = t + it * 256;
        float4 v = ((const float4*)yp)[i];
        int m = i >> 6, c4 = (i & 63) * 4;
        *(float4*)&ylds[m * 260 + c4] = v;
    }
    // stage qk bf16 -> fp32
    #pragma unroll
    for (int it = 0; it < 2; ++it) {
        int i = t + it * 256;
        uint2 v = ((const uint2*)qkp)[i];
        int h = i >> 6, c4 = (i & 63) * 4;
        float4 f = make_float4(bfl(v.x), bfh(v.x), bfl(v.y), bfh(v.y));
        *(float4*)&qkf[h * 260 + c4] = f;
    }
    __syncthreads();

    // dots: thread (m = t&15, cs = t>>4) covers c = cs*16 .. +15, all 8 heads
    {
        const int m = t & 15, cs = t >> 4;
        float ps[8] = {0.f, 0.f, 0.f, 0.f, 0.f, 0.f, 0.f, 0.f};
        #pragma unroll
        for (int jj = 0; jj < 4; ++jj) {
            float4 yv = *(const float4*)&ylds[m * 260 + cs * 16 + jj * 4];
            #pragma unroll
            for (int h = 0; h < 8; ++h) {
                float4 qv = *(const float4*)&qkf[h * 260 + cs * 16 + jj * 4];
                ps[h] += yv.x * qv.x + yv.y * qv.y + yv.z * qv.z + yv.w * qv.w;
            }
        }
        #pragma unroll
        for (int h = 0; h < 8; ++h) {
            float s = ps[h];
            s += __shfl_xor(s, 16);
            s += __shfl_xor(s, 32);
            if (lane < 16) part[w][h][m] = s;
        }
    }
    __syncthreads();

    // softmax over m (16) per head; threads 0..127: h = t>>4, mm = t&15
    if (t < 128) {
        const int h = t >> 4, mm = t & 15;
        float d = (part[0][h][mm] + part[1][h][mm] + part[2][h][mm] + part[3][h][mm]) * ATT_SCALE;
        float mx = d;
        #pragma unroll
        for (int off = 8; off >= 1; off >>= 1) mx = fmaxf(mx, __shfl_xor(mx, off));
        float e = __expf(d - mx);
        float sm = e;
        #pragma unroll
        for (int off = 8; off >= 1; off >>= 1) sm += __shfl_xor(sm, off);
        attn_sT[mm][h] = e / sm;
    }
    __syncthreads();

    // ybar[h, c=t] = sum_m attn[h,m] * y[m,c]; overwrite qk (bf16)
    {
        float acc[8] = {0.f, 0.f, 0.f, 0.f, 0.f, 0.f, 0.f, 0.f};
        #pragma unroll
        for (int mm = 0; mm < 16; ++mm) {
            float yv = ylds[mm * 260 + t];
            float4 a0 = *(const float4*)&attn_sT[mm][0];
            float4 a1 = *(const float4*)&attn_sT[mm][4];
            acc[0] = fmaf(a0.x, yv, acc[0]);
            acc[1] = fmaf(a0.y, yv, acc[1]);
            acc[2] = fmaf(a0.z, yv, acc[2]);
            acc[3] = fmaf(a0.w, yv, acc[3]);
            acc[4] = fmaf(a1.x, yv, acc[4]);
            acc[5] = fmaf(a1.y, yv, acc[5]);
            acc[6] = fmaf(a1.z, yv, acc[6]);
            acc[7] = fmaf(a1.w, yv, acc[7]);
        }
        #pragma unroll
        for (int h = 0; h < 8; ++h) qkp[h * 256 + t] = f2bf(acc[h]);
    }
}

extern "C" void kernel_launch(void* const* d_in, const int* in_sizes, int n_in,
                              void* d_out, int out_size, void* d_ws, size_t ws_size,
                              hipStream_t stream)
{
    (void)in_sizes; (void)n_in; (void)out_size; (void)ws_size;
    const float* x     = (const float*)d_in[0];   // [16384,256]
    const float* y     = (const float*)d_in[1];   // [16384,16,256]
    const float* W_q   = (const float*)d_in[2];   // [256,512]
    const float* W_kv  = (const float*)d_in[3];   // [256,1024]
    const float* W_out = (const float*)d_in[4];   // [512,256]
    const float* b_out = (const float*)d_in[5];   // [256]
    float* out = (float*)d_out;                   // [16384,256]

    // workspace: qk/ybar [16384,2048] bf16 (67MB), xb [16384,256] bf16 (8.4MB),
    //            Wf1n [2048,256] bf16 (1MB), Wf2t [256,2048] bf16 (1MB)
    ushort* qk   = (ushort*)d_ws;
    ushort* xb   = qk + (size_t)NPOS * 2048;
    ushort* Wf1n = xb + (size_t)NPOS * 256;
    ushort* Wf2t = Wf1n + 2048 * 256;

    dim3 blk(256);

    prep_x<<<dim3(2048), blk, 0, stream>>>(x, xb);
    prep_w<<<dim3(4096), blk, 0, stream>>>(W_q, W_kv, W_out, Wf1n, Wf2t);

    // K1: qk = xb @ Wf1n^T   [16384,256] x [256,2048] -> bf16 [16384,2048]
    gemm_bt<128, false, false><<<dim3(16, 128), blk, 0, stream>>>(
        xb, 256, Wf1n, 256, qk, 2048, nullptr, 256);

    // K2: attention in place over qk
    attn_k<<<dim3(NPOS), blk, 0, stream>>>(y, qk);

    // K3: out = ybar @ Wf2t^T + b_out   [16384,2048] x [2048,256] -> fp32
    gemm_bt<64, true, true><<<dim3(4, 128), blk, 0, stream>>>(
        qk, 2048, Wf2t, 2048, out, 256, b_out, 2048);
}

// Round 4
// 489.154 us; speedup vs baseline: 1.9233x; 1.0691x over previous
//
#include <hip/hip_runtime.h>
#include <cmath>

#define NPOS 16384
#define ATT_SCALE 0.125f

typedef float f4 __attribute__((ext_vector_type(4)));
typedef short short8 __attribute__((ext_vector_type(8)));
typedef unsigned int uint;
typedef unsigned short ushort;

__device__ __forceinline__ ushort f2bf(float f) {
    union { float f; uint u; } v; v.f = f;
    uint r = v.u + 0x7fffu + ((v.u >> 16) & 1u);
    return (ushort)(r >> 16);
}
__device__ __forceinline__ float bfl(uint u) { union { uint u; float f; } v; v.u = u << 16; return v.f; }
__device__ __forceinline__ float bfh(uint u) { union { uint u; float f; } v; v.u = u & 0xffff0000u; return v.f; }

// async global->LDS, 16B per lane; LDS dest = base + lane*16 (wave-uniform base)
__device__ __forceinline__ void gl_lds16(const ushort* g, ushort* l) {
    __builtin_amdgcn_global_load_lds(
        (const __attribute__((address_space(1))) uint*)g,
        (__attribute__((address_space(3))) uint*)l, 16, 0, 0);
}

// ---------------------------------------------------------------------------
// bf16 MFMA GEMM (m97-style): C[M,N] = A[M,K] @ Bt[N,K]^T (+bias)
// BM=128, BN = 128 or 64, BK=32, 256 threads = 4 waves.
// MFMA operands swapped -> acc holds C^T: lane frow = C-row, (quad*4+i) = C-col
// so each lane owns 4 consecutive C columns -> packed stores.
// ---------------------------------------------------------------------------
template<int BN, bool C_F32, bool BIAS>
__global__ __launch_bounds__(256) void gemm_bt(
    const ushort* __restrict__ A, int lda,
    const ushort* __restrict__ Bt, int ldb,
    void* __restrict__ Cg, int ldc,
    const float* __restrict__ bias, int K)
{
    constexpr int NSUB = BN / 16;
    __shared__ __align__(16) ushort A_lds[128 * 32];
    __shared__ __align__(16) ushort B_lds[BN * 32];
    const int nt = blockIdx.x, mt = blockIdx.y;
    const int row0 = mt * 128, col0 = nt * BN;
    const int tid = threadIdx.x;
    const int lane = tid & 63, w = tid >> 6;
    const int frow = lane & 15, quad = lane >> 4;
    const int lrow = lane >> 2, lk = (lane & 3) * 8;

    f4 acc[2][NSUB];
    #pragma unroll
    for (int mi = 0; mi < 2; ++mi)
        #pragma unroll
        for (int ni = 0; ni < NSUB; ++ni)
            acc[mi][ni] = (f4){0.f, 0.f, 0.f, 0.f};

    for (int k0 = 0; k0 < K; k0 += 32) {
        #pragma unroll
        for (int it = 0; it < 2; ++it) {
            int start = w * 16 + it * 64;
            gl_lds16(A + (size_t)(row0 + start + lrow) * lda + k0 + lk,
                     &A_lds[start * 32]);
        }
        #pragma unroll
        for (int it = 0; it < BN / 64; ++it) {
            int start = w * 16 + it * 64;
            gl_lds16(Bt + (size_t)(col0 + start + lrow) * ldb + k0 + lk,
                     &B_lds[start * 32]);
        }
        __syncthreads();

        short8 a0 = *(const short8*)&A_lds[(w * 32 + frow) * 32 + quad * 8];
        short8 a1 = *(const short8*)&A_lds[(w * 32 + 16 + frow) * 32 + quad * 8];
        #pragma unroll
        for (int ni = 0; ni < NSUB; ++ni) {
            short8 b = *(const short8*)&B_lds[(ni * 16 + frow) * 32 + quad * 8];
            acc[0][ni] = __builtin_amdgcn_mfma_f32_16x16x32_bf16(b, a0, acc[0][ni], 0, 0, 0);
            acc[1][ni] = __builtin_amdgcn_mfma_f32_16x16x32_bf16(b, a1, acc[1][ni], 0, 0, 0);
        }
        __syncthreads();
    }

    #pragma unroll
    for (int mi = 0; mi < 2; ++mi) {
        const int r = row0 + w * 32 + mi * 16 + frow;
        #pragma unroll
        for (int ni = 0; ni < NSUB; ++ni) {
            const int c = col0 + ni * 16 + quad * 4;
            f4 v = acc[mi][ni];
            if (C_F32) {
                float* C = (float*)Cg;
                if (BIAS) {
                    const float4 bv = *(const float4*)&bias[c];
                    v[0] += bv.x; v[1] += bv.y; v[2] += bv.z; v[3] += bv.w;
                }
                *(float4*)&C[(size_t)r * ldc + c] = make_float4(v[0], v[1], v[2], v[3]);
            } else {
                ushort* C = (ushort*)Cg;
                uint2 pv;
                pv.x = (uint)f2bf(v[0]) | ((uint)f2bf(v[1]) << 16);
                pv.y = (uint)f2bf(v[2]) | ((uint)f2bf(v[3]) << 16);
                *(uint2*)&C[(size_t)r * ldc + c] = pv;
            }
        }
    }
}

// ---------------------------------------------------------------------------
// prep_x: x fp32 -> bf16, 8 elems/thread
// ---------------------------------------------------------------------------
__global__ __launch_bounds__(256) void prep_x(
    const float* __restrict__ x, ushort* __restrict__ xb)
{
    const int i = (blockIdx.x * 256 + threadIdx.x) * 8;
    float4 v0 = *(const float4*)&x[i];
    float4 v1 = *(const float4*)&x[i + 4];
    uint4 p;
    p.x = (uint)f2bf(v0.x) | ((uint)f2bf(v0.y) << 16);
    p.y = (uint)f2bf(v0.z) | ((uint)f2bf(v0.w) << 16);
    p.z = (uint)f2bf(v1.x) | ((uint)f2bf(v1.y) << 16);
    p.w = (uint)f2bf(v1.z) | ((uint)f2bf(v1.w) << 16);
    *(uint4*)&xb[i] = p;
}

// ---------------------------------------------------------------------------
// prep_fuse: weight fusion as tiled LDS fp32 GEMMs (coalesced).
// Blocks 0..127  : Wf1n[(h*256+c)][e] = sum_d Wq[e,64h+d]*Wkv[c,64h+d]
// Blocks 128..255: Wf2t[e][h*256+c]   = sum_d Wkv[c,512+64h+d]*Wout[64h+d,e]
// Tile 64x64 (ct x et), K=64. 256 threads, 4x4 acc each.
// ---------------------------------------------------------------------------
__global__ __launch_bounds__(256) void prep_fuse(
    const float* __restrict__ Wq, const float* __restrict__ Wkv,
    const float* __restrict__ Wout,
    ushort* __restrict__ Wf1n, ushort* __restrict__ Wf2t)
{
    __shared__ float As[64][65];   // A[c][d]
    __shared__ float Bs[64][65];   // phase1: B[e][d]; phase2: B[d][e]
    const int b = blockIdx.x;
    const bool second = (b >= 128);
    const int bb = second ? b - 128 : b;
    const int h = bb >> 4, ct = (bb >> 2) & 3, et = bb & 3;
    const int t = threadIdx.x;
    const int c0 = ct * 64, e0 = et * 64;
    const int tx = t & 15, ty = t >> 4;

    // stage A[c][d]: rows of Wkv (coalesced)
    const float* Ab = Wkv + (second ? 512 : 0) + h * 64;
    #pragma unroll
    for (int it = 0; it < 4; ++it) {
        int idx = t + it * 256;
        int row = idx >> 4, col = (idx & 15) * 4;
        float4 v = *(const float4*)&Ab[(size_t)(c0 + row) * 1024 + col];
        As[row][col] = v.x; As[row][col + 1] = v.y;
        As[row][col + 2] = v.z; As[row][col + 3] = v.w;
    }
    // stage B
    #pragma unroll
    for (int it = 0; it < 4; ++it) {
        int idx = t + it * 256;
        int row = idx >> 4, col = (idx & 15) * 4;
        float4 v;
        if (second) // B[d][e] = Wout[(64h+d)*256 + e0+e]  (row=d, col=e)
            v = *(const float4*)&Wout[(size_t)(h * 64 + row) * 256 + e0 + col];
        else        // B[e][d] = Wq[(e0+e)*512 + 64h + d]  (row=e, col=d)
            v = *(const float4*)&Wq[(size_t)(e0 + row) * 512 + h * 64 + col];
        Bs[row][col] = v.x; Bs[row][col + 1] = v.y;
        Bs[row][col + 2] = v.z; Bs[row][col + 3] = v.w;
    }
    __syncthreads();

    float acc[4][4] = {};
    if (!second) {
        // C[c][e]: c = ty*4+i, e = tx*4+j
        for (int k = 0; k < 64; ++k) {
            float a[4], bb2[4];
            #pragma unroll
            for (int i = 0; i < 4; ++i) a[i] = As[ty * 4 + i][k];
            #pragma unroll
            for (int j = 0; j < 4; ++j) bb2[j] = Bs[tx * 4 + j][k];
            #pragma unroll
            for (int i = 0; i < 4; ++i)
                #pragma unroll
                for (int j = 0; j < 4; ++j)
                    acc[i][j] = fmaf(a[i], bb2[j], acc[i][j]);
        }
        #pragma unroll
        for (int i = 0; i < 4; ++i) {
            int c = c0 + ty * 4 + i;
            uint2 pv;
            pv.x = (uint)f2bf(acc[i][0]) | ((uint)f2bf(acc[i][1]) << 16);
            pv.y = (uint)f2bf(acc[i][2]) | ((uint)f2bf(acc[i][3]) << 16);
            *(uint2*)&Wf1n[(size_t)(h * 256 + c) * 256 + e0 + tx * 4] = pv;
        }
    } else {
        // C[e][c]: e = ty*4+i, c = tx*4+j
        for (int k = 0; k < 64; ++k) {
            float a[4], bb2[4];
            #pragma unroll
            for (int j = 0; j < 4; ++j) a[j] = As[tx * 4 + j][k];   // A[c][d=k]
            #pragma unroll
            for (int i = 0; i < 4; ++i) bb2[i] = Bs[k][ty * 4 + i]; // B[d=k][e]
            #pragma unroll
            for (int i = 0; i < 4; ++i)
                #pragma unroll
                for (int j = 0; j < 4; ++j)
                    acc[i][j] = fmaf(bb2[i], a[j], acc[i][j]);
        }
        #pragma unroll
        for (int i = 0; i < 4; ++i) {
            int e = e0 + ty * 4 + i;
            uint2 pv;
            pv.x = (uint)f2bf(acc[i][0]) | ((uint)f2bf(acc[i][1]) << 16);
            pv.y = (uint)f2bf(acc[i][2]) | ((uint)f2bf(acc[i][3]) << 16);
            *(uint2*)&Wf2t[(size_t)e * 2048 + h * 256 + c0 + tx * 4] = pv;
        }
    }
}

// ---------------------------------------------------------------------------
// attn: one position per 256-thread block. y (16 KB) + qk staged to LDS once;
// dots -> softmax -> ybar; ybar overwrites qk (bf16). y read from HBM once.
// ---------------------------------------------------------------------------
__global__ __launch_bounds__(256) void attn_k(
    const float* __restrict__ y, ushort* __restrict__ qk)
{
    __shared__ float ylds[16 * 260];
    __shared__ float qkf[8 * 260];
    __shared__ float part[4][8][16];
    __shared__ __align__(16) float attn_sT[16][8];
    const int p = blockIdx.x;
    const int t = threadIdx.x;
    const int w = t >> 6, lane = t & 63;
    const float* yp = y + (size_t)p * 4096;
    ushort* qkp = qk + (size_t)p * 2048;

    #pragma unroll
    for (int it = 0; it < 4; ++it) {
        int i = t + it * 256;
        float4 v = ((const float4*)yp)[i];
        int m = i >> 6, c4 = (i & 63) * 4;
        *(float4*)&ylds[m * 260 + c4] = v;
    }
    #pragma unroll
    for (int it = 0; it < 2; ++it) {
        int i = t + it * 256;
        uint2 v = ((const uint2*)qkp)[i];
        int h = i >> 6, c4 = (i & 63) * 4;
        float4 f = make_float4(bfl(v.x), bfh(v.x), bfl(v.y), bfh(v.y));
        *(float4*)&qkf[h * 260 + c4] = f;
    }
    __syncthreads();

    {
        const int m = t & 15, cs = t >> 4;
        float ps[8] = {0.f, 0.f, 0.f, 0.f, 0.f, 0.f, 0.f, 0.f};
        #pragma unroll
        for (int jj = 0; jj < 4; ++jj) {
            float4 yv = *(const float4*)&ylds[m * 260 + cs * 16 + jj * 4];
            #pragma unroll
            for (int h = 0; h < 8; ++h) {
                float4 qv = *(const float4*)&qkf[h * 260 + cs * 16 + jj * 4];
                ps[h] += yv.x * qv.x + yv.y * qv.y + yv.z * qv.z + yv.w * qv.w;
            }
        }
        #pragma unroll
        for (int h = 0; h < 8; ++h) {
            float s = ps[h];
            s += __shfl_xor(s, 16);
            s += __shfl_xor(s, 32);
            if (lane < 16) part[w][h][m] = s;
        }
    }
    __syncthreads();

    if (t < 128) {
        const int h = t >> 4, mm = t & 15;
        float d = (part[0][h][mm] + part[1][h][mm] + part[2][h][mm] + part[3][h][mm]) * ATT_SCALE;
        float mx = d;
        #pragma unroll
        for (int off = 8; off >= 1; off >>= 1) mx = fmaxf(mx, __shfl_xor(mx, off));
        float e = __expf(d - mx);
        float sm = e;
        #pragma unroll
        for (int off = 8; off >= 1; off >>= 1) sm += __shfl_xor(sm, off);
        attn_sT[mm][h] = e / sm;
    }
    __syncthreads();

    {
        float acc[8] = {0.f, 0.f, 0.f, 0.f, 0.f, 0.f, 0.f, 0.f};
        #pragma unroll
        for (int mm = 0; mm < 16; ++mm) {
            float yv = ylds[mm * 260 + t];
            float4 a0 = *(const float4*)&attn_sT[mm][0];
            float4 a1 = *(const float4*)&attn_sT[mm][4];
            acc[0] = fmaf(a0.x, yv, acc[0]);
            acc[1] = fmaf(a0.y, yv, acc[1]);
            acc[2] = fmaf(a0.z, yv, acc[2]);
            acc[3] = fmaf(a0.w, yv, acc[3]);
            acc[4] = fmaf(a1.x, yv, acc[4]);
            acc[5] = fmaf(a1.y, yv, acc[5]);
            acc[6] = fmaf(a1.z, yv, acc[6]);
            acc[7] = fmaf(a1.w, yv, acc[7]);
        }
        #pragma unroll
        for (int h = 0; h < 8; ++h) qkp[h * 256 + t] = f2bf(acc[h]);
    }
}

extern "C" void kernel_launch(void* const* d_in, const int* in_sizes, int n_in,
                              void* d_out, int out_size, void* d_ws, size_t ws_size,
                              hipStream_t stream)
{
    (void)in_sizes; (void)n_in; (void)out_size; (void)ws_size;
    const float* x     = (const float*)d_in[0];
    const float* y     = (const float*)d_in[1];
    const float* W_q   = (const float*)d_in[2];
    const float* W_kv  = (const float*)d_in[3];
    const float* W_out = (const float*)d_in[4];
    const float* b_out = (const float*)d_in[5];
    float* out = (float*)d_out;

    ushort* qk   = (ushort*)d_ws;
    ushort* xb   = qk + (size_t)NPOS * 2048;
    ushort* Wf1n = xb + (size_t)NPOS * 256;
    ushort* Wf2t = Wf1n + 2048 * 256;

    dim3 blk(256);

    prep_x<<<dim3(2048), blk, 0, stream>>>(x, xb);
    prep_fuse<<<dim3(256), blk, 0, stream>>>(W_q, W_kv, W_out, Wf1n, Wf2t);

    // K1: qk = xb @ Wf1n^T   [16384,256] x [256,2048] -> bf16
    gemm_bt<128, false, false><<<dim3(16, 128), blk, 0, stream>>>(
        xb, 256, Wf1n, 256, qk, 2048, nullptr, 256);

    // K2: attention in place over qk
    attn_k<<<dim3(NPOS), blk, 0, stream>>>(y, qk);

    // K3: out = ybar @ Wf2t^T + b_out   [16384,2048] x [2048,256] -> fp32
    gemm_bt<64, true, true><<<dim3(4, 128), blk, 0, stream>>>(
        qk, 2048, Wf2t, 2048, out, 256, b_out, 2048);
}